// Round 25
// baseline (349.567 us; speedup 1.0000x reference)
//
#include <hip/hip_runtime.h>
#include <cstdint>
#include <cstddef>

// ---------------- common types / helpers ----------------
typedef __attribute__((ext_vector_type(8))) short bf16x8;
typedef __attribute__((ext_vector_type(4))) float f32x4;
typedef __attribute__((ext_vector_type(16))) float f32x16;

#define S_LEN 2048
#define SCALE2 0.10411754f   // 192^-0.5 * log2(e)

__device__ __forceinline__ ushort f2bf(float f) {
  uint32_t u = __float_as_uint(f);
  u = (u + 0x7FFFu + ((u >> 16) & 1u)) >> 16;
  return (ushort)u;
}
__device__ __forceinline__ float bf2f(ushort u) {
  return __uint_as_float(((uint32_t)u) << 16);
}

typedef __attribute__((address_space(1))) void GV;
typedef __attribute__((address_space(3))) void LV;
__device__ __forceinline__ void gload16(const void* g, void* l) {
  __builtin_amdgcn_global_load_lds((GV*)g, (LV*)l, 16, 0, 0);
}

__device__ __forceinline__ void store_out(float* p, float v) { *p = v; }
__device__ __forceinline__ void store_out(ushort* p, float v) { *p = f2bf(v); }

// ---------------- merged preprocessing: 5 weight transposes + x convert ----------------
__global__ void k_pre(const float* __restrict__ s0, const float* __restrict__ s1,
                      const float* __restrict__ s2, const float* __restrict__ s3,
                      const float* __restrict__ s4,
                      ushort* __restrict__ d0, ushort* __restrict__ d1,
                      ushort* __restrict__ d2, ushort* __restrict__ d3,
                      ushort* __restrict__ d4,
                      const float* __restrict__ x, ushort* __restrict__ xb) {
  int id = blockIdx.x;
  if (id >= 14976) {            // convert segment: 2048 blocks, grid-stride
    int ft = threadIdx.y * 32 + threadIdx.x;
    int i = (id - 14976) * 256 + ft;
    const int n4 = 4096 * 2048 / 4, stride = 2048 * 256;
    for (; i < n4; i += stride) {
      float4 v = reinterpret_cast<const float4*>(x)[i];
      ushort4 o;
      o.x = f2bf(v.x); o.y = f2bf(v.y); o.z = f2bf(v.z); o.w = f2bf(v.w);
      reinterpret_cast<ushort4*>(xb)[i] = o;
    }
    return;
  }
  __shared__ float tile[32][33];
  const float* in; ushort* out; int R, C, gx, lid;
  if (id < 3072)        { in = s0; out = d0; R = 2048; C = 1536; gx = 48;  lid = id; }
  else if (id < 4224)   { in = s1; out = d1; R = 2048; C = 576;  gx = 18;  lid = id - 3072; }
  else if (id < 8832)   { in = s2; out = d2; R = 1536; C = 3072; gx = 96;  lid = id - 4224; }
  else if (id < 10880)  { in = s3; out = d3; R = 512;  C = 4096; gx = 128; lid = id - 8832; }
  else                  { in = s4; out = d4; R = 2048; C = 2048; gx = 64;  lid = id - 10880; }
  int c0 = (lid % gx) * 32, r0 = (lid / gx) * 32;
  int tx = threadIdx.x, ty = threadIdx.y;
#pragma unroll
  for (int i = 0; i < 32; i += 8) {
    int r = r0 + ty + i, c = c0 + tx;
    if (r < R && c < C) tile[ty + i][tx] = in[(size_t)r * C + c];
  }
  __syncthreads();
#pragma unroll
  for (int i = 0; i < 32; i += 8) {
    int c = c0 + ty + i, r = r0 + tx;
    if (r < R && c < C) out[(size_t)c * R + r] = f2bf(tile[tx][ty + i]);
  }
}

// ---------------- 128x128 BK=64 bf16 GEMM, dbuf counted-vmcnt (R24-proven protocol) ----------------
// R25 delta vs R15 form: double-buffer (72KB -> 2 blocks/CU) with the COUNTED
// schedule proven in R24's qkv256. Waves carry 8 or 10 loads per stage (the
// ii<18 guard is wave-uniform: waves 0,1 do 5 iters x2, waves 2,3 do 4x2);
// vmcnt(8) is exact for 8-load waves and conservative (+2) for 10-load waves.
// Boundary iters (kt==0: prologue order; kt==nt-1: nothing staged ahead)
// drain to vmcnt(0) -- the R9/R10 counting lesson. Raw s_barrier + fences
// (barrier has no memory semantics). R16's failure was draining vmcnt(0)
// AFTER issuing the prefetch -- pure TLP loss; counted waits fix that.
template <typename OUT>
__global__ __launch_bounds__(256) void k_gemm(const ushort* __restrict__ A,
                                              const ushort* __restrict__ Bt,
                                              OUT* __restrict__ C, int K, int Nreal) {
  __shared__ ushort As[2][128 * 72];   // 2 x 18432 B
  __shared__ ushort Bs[2][128 * 72];
  const int t = threadIdx.x, lane = t & 63, w = t >> 6;
  const int nwg = gridDim.x * gridDim.y;
  const int wg = blockIdx.y * gridDim.x + blockIdx.x;
  const int swz = (wg & 7) * (nwg >> 3) + (wg >> 3);
  const int m0 = (swz / gridDim.x) * 128, n0 = (swz % gridDim.x) * 128;
  const int wm = (w >> 1) * 64, wn = (w & 1) * 64;
  const int g = lane >> 4, q = lane & 15;
  const int nt = K >> 6;

  auto stage = [&](int kt, int p) {
#pragma unroll
    for (int it = 0; it < 5; ++it) {
      int ii = it * 4 + w;
      if (ii < 18) {
        unsigned s = ii * 64 + lane;         // 0..1151
        int r = s / 9, e = s - r * 9;        // r<128, e<9
        int cg = e ^ ((r >> 3) & 7);
        if (cg > 7) cg = 0;                  // pad slot -> dummy load
        gload16(A + (size_t)(m0 + r) * K + kt * 64 + cg * 8, (char*)&As[p][0] + ii * 1024);
        gload16(Bt + (size_t)(n0 + r) * K + kt * 64 + cg * 8, (char*)&Bs[p][0] + ii * 1024);
      }
    }
  };

  f32x4 acc[4][4] = {};
  stage(0, 0);
  asm volatile("" ::: "memory");             // pin prologue issue order
  stage(1, 1);

  for (int kt = 0; kt < nt; ++kt) {
    const int p = kt & 1;
    if (kt == 0 || kt + 1 >= nt) asm volatile("s_waitcnt vmcnt(0)" ::: "memory");
    else                         asm volatile("s_waitcnt vmcnt(8)" ::: "memory");
    __builtin_amdgcn_s_barrier();
    asm volatile("" ::: "memory");           // ds_reads must stay below barrier
#pragma unroll
    for (int kh = 0; kh < 2; ++kh) {
      bf16x8 af[4], bfr[4];
#pragma unroll
      for (int mi = 0; mi < 4; mi++) {
        int row = wm + 16 * mi + q;
        int rx = (row >> 3) & 7;
        af[mi] = *(const bf16x8*)(&As[p][0] + row * 72 + (((kh * 4 + g) ^ rx) << 3));
      }
#pragma unroll
      for (int ni = 0; ni < 4; ni++) {
        int row = wn + 16 * ni + q;
        int rx = (row >> 3) & 7;
        bfr[ni] = *(const bf16x8*)(&Bs[p][0] + row * 72 + (((kh * 4 + g) ^ rx) << 3));
      }
#pragma unroll
      for (int mi = 0; mi < 4; mi++)
#pragma unroll
        for (int ni = 0; ni < 4; ni++)
          acc[mi][ni] = __builtin_amdgcn_mfma_f32_16x16x32_bf16(af[mi], bfr[ni], acc[mi][ni], 0, 0, 0);
    }
    asm volatile("s_waitcnt lgkmcnt(0)" ::: "memory");
    __builtin_amdgcn_s_barrier();
    asm volatile("" ::: "memory");           // stage must stay below barrier
    if (kt + 2 < nt) stage(kt + 2, p);
  }

#pragma unroll
  for (int mi = 0; mi < 4; mi++)
#pragma unroll
    for (int ni = 0; ni < 4; ni++) {
      int col = n0 + wn + 16 * ni + q;
      if (col < Nreal) {
        int row = m0 + wm + 16 * mi + 4 * g;
#pragma unroll
        for (int r = 0; r < 4; r++)
          store_out(&C[(size_t)(row + r) * Nreal + col], acc[mi][ni][r]);
      }
    }
}

// ---------------- merged GEMM2(qrope)+GEMM-kv: 256x256 BK=64 dbuf counted-vmcnt (R24-proven) ----------------
__global__ __launch_bounds__(512, 1) void k_gemm_qkv256(
    const ushort* __restrict__ A1, const ushort* __restrict__ Bt1,
    ushort* __restrict__ C1,
    const float* __restrict__ cosT, const float* __restrict__ sinT,
    const ushort* __restrict__ A2, const ushort* __restrict__ Bt2,
    ushort* __restrict__ kbuf, ushort* __restrict__ vT) {
  __shared__ __align__(16) char lds[2][4][18432];
  const int t = threadIdx.x, lane = t & 63, w = t >> 6;
  const int q = lane & 15, g = lane >> 4;
  const int wm = w >> 2, wn = w & 3;
  const int id = blockIdx.x;
  const bool seg1 = (id < 192);
  const ushort* A  = seg1 ? A1 : A2;
  const ushort* Bt = seg1 ? Bt1 : Bt2;
  const int K   = seg1 ? 1536 : 512;
  const int gx  = seg1 ? 12 : 16;
  const int nwg = seg1 ? 192 : 256;
  const int wg  = seg1 ? id : id - 192;
  const int swz = (wg & 7) * (nwg >> 3) + (wg >> 3);
  const int m0 = (swz / gx) * 256, n0 = (swz % gx) * 256;
  const int nt = K >> 6;

  auto stageTile = [&](int kt, int p) {
#pragma unroll
    for (int it = 0; it < 9; ++it) {
      int u = it * 512 + (w << 6);
      int hh = u / 1152;
      int s0 = u - hh * 1152;
      int s = s0 + lane;
      int r = s / 9, c = s - r * 9;
      if (c > 7) c = 0;
      const ushort* src = (hh < 2) ? (A + (size_t)(m0 + (hh << 7) + r) * K)
                                   : (Bt + (size_t)(n0 + ((hh - 2) << 7) + r) * K);
      gload16(src + kt * 64 + c * 8, &lds[p][hh][s0 * 16]);
    }
  };

  f32x4 acc[8][4] = {};
  stageTile(0, 0);
  asm volatile("" ::: "memory");
  stageTile(1, 1);

  for (int kt = 0; kt < nt; ++kt) {
    const int p = kt & 1;
    if (kt == 0 || kt + 1 >= nt) asm volatile("s_waitcnt vmcnt(0)" ::: "memory");
    else                         asm volatile("s_waitcnt vmcnt(9)" ::: "memory");
    __builtin_amdgcn_s_barrier();
    asm volatile("" ::: "memory");
    const char* LA = &lds[p][wm][0];
    const char* LB = &lds[p][2 + (wn >> 1)][0];
    const int brow0 = (wn & 1) * 64;
    bf16x8 bfr[4][2];
#pragma unroll
    for (int ni = 0; ni < 4; ++ni) {
      bfr[ni][0] = *(const bf16x8*)(LB + (brow0 + ni * 16 + q) * 144 + 16 * g);
      bfr[ni][1] = *(const bf16x8*)(LB + (brow0 + ni * 16 + q) * 144 + 64 + 16 * g);
    }
    __builtin_amdgcn_s_setprio(1);
#pragma unroll
    for (int mi = 0; mi < 8; ++mi) {
      bf16x8 a0 = *(const bf16x8*)(LA + (mi * 16 + q) * 144 + 16 * g);
      bf16x8 a1 = *(const bf16x8*)(LA + (mi * 16 + q) * 144 + 64 + 16 * g);
#pragma unroll
      for (int ni = 0; ni < 4; ++ni)
        acc[mi][ni] = __builtin_amdgcn_mfma_f32_16x16x32_bf16(a0, bfr[ni][0], acc[mi][ni], 0, 0, 0);
#pragma unroll
      for (int ni = 0; ni < 4; ++ni)
        acc[mi][ni] = __builtin_amdgcn_mfma_f32_16x16x32_bf16(a1, bfr[ni][1], acc[mi][ni], 0, 0, 0);
    }
    __builtin_amdgcn_s_setprio(0);
    asm volatile("s_waitcnt lgkmcnt(0)" ::: "memory");
    __builtin_amdgcn_s_barrier();
    asm volatile("" ::: "memory");
    if (kt + 2 < nt) stageTile(kt + 2, p);
  }

  if (seg1) {
#pragma unroll
    for (int mi = 0; mi < 8; ++mi)
#pragma unroll
      for (int ni = 0; ni < 4; ++ni) {
        int col = n0 + wn * 64 + ni * 16 + q;
        int hoff = col % 192;
        int row = m0 + wm * 128 + mi * 16 + 4 * g;
        if (hoff < 128) {
#pragma unroll
          for (int r = 0; r < 4; r++)
            C1[(size_t)(row + r) * 3072 + col] = f2bf(acc[mi][ni][r]);
        } else {
          int i = (hoff - 128) >> 1;
#pragma unroll
          for (int r = 0; r < 4; r++) {
            int s2 = (row + r) & 2047;
            float c = cosT[s2 * 32 + i], sn = sinT[s2 * 32 + i];
            float v = acc[mi][ni][r];
            float pv = __shfl_xor(v, 1);
            float res = (q & 1) ? (pv * sn + v * c) : (v * c - pv * sn);
            C1[(size_t)(row + r) * 3072 + col] = f2bf(res);
          }
        }
      }
  } else {
#pragma unroll
    for (int mi = 0; mi < 8; ++mi)
#pragma unroll
      for (int ni = 0; ni < 4; ++ni) {
        int col = n0 + wn * 64 + ni * 16 + q;
        int hh = col >> 8, jj = col & 255;
        int row0 = m0 + wm * 128 + mi * 16 + 4 * g;
#pragma unroll
        for (int r = 0; r < 4; r++) {
          int tok = row0 + r;
          int bb = tok >> 11, ss = tok & 2047;
          ushort v = f2bf(acc[mi][ni][r]);
          if (jj < 128)
            kbuf[((size_t)(bb * 16 + hh) * 2048 + ss) * 192 + jj] = v;
          else
            vT[((size_t)(bb * 16 + hh) * 128 + (jj - 128)) * 2048 + ss] = v;
        }
      }
  }
}

// ---------------- merged norms: rmsnorm(q) + kvnorm+rope (8192 blocks) ----------------
__global__ void k_norms(const ushort* __restrict__ cqkv, const float* __restrict__ qnw,
                        const float* __restrict__ kvnw,
                        const float* __restrict__ cosT, const float* __restrict__ sinT,
                        ushort* __restrict__ cqn, ushort* __restrict__ ckvn,
                        ushort* __restrict__ kbuf) {
  __shared__ float red[4];
  int id = blockIdx.x;
  if (id < 4096) {
    int row = id;
    const ushort* x = cqkv + (size_t)row * 2112;
    ushort* o = cqn + (size_t)row * 1536;
    float ss = 0.f;
    for (int i = threadIdx.x; i < 1536; i += 256) { float v = bf2f(x[i]); ss += v * v; }
#pragma unroll
    for (int m = 1; m < 64; m <<= 1) ss += __shfl_xor(ss, m);
    if ((threadIdx.x & 63) == 0) red[threadIdx.x >> 6] = ss;
    __syncthreads();
    float tot = red[0] + red[1] + red[2] + red[3];
    float sc = rsqrtf(tot / 1536.f + 1e-6f);
    for (int i = threadIdx.x; i < 1536; i += 256) o[i] = f2bf(bf2f(x[i]) * sc * qnw[i]);
  } else {
    int tok = id - 4096, b = tok >> 11, s = tok & 2047;
    const ushort* x = cqkv + (size_t)tok * 2112 + 1536;
    float ss = 0.f;
    for (int i = threadIdx.x; i < 512; i += 256) { float v = bf2f(x[i]); ss += v * v; }
#pragma unroll
    for (int m = 1; m < 64; m <<= 1) ss += __shfl_xor(ss, m);
    if ((threadIdx.x & 63) == 0) red[threadIdx.x >> 6] = ss;
    __syncthreads();
    float tot = red[0] + red[1] + red[2] + red[3];
    float sc = rsqrtf(tot / 512.f + 1e-6f);
    for (int i = threadIdx.x; i < 512; i += 256) ckvn[(size_t)tok * 512 + i] = f2bf(bf2f(x[i]) * sc * kvnw[i]);
    if (threadIdx.x < 32) {
      int i = threadIdx.x;
      float xr = bf2f(x[512 + 2 * i]), xi = bf2f(x[512 + 2 * i + 1]);
      float c = cosT[s * 32 + i], sn = sinT[s * 32 + i];
      uint32_t lo = f2bf(xr * c - xi * sn);
      uint32_t hi = f2bf(xr * sn + xi * c);
      uint32_t pk = lo | (hi << 16);
#pragma unroll
      for (int h = 0; h < 16; ++h)
        *(uint32_t*)(kbuf + ((size_t)(b * 16 + h) * 2048 + s) * 192 + 128 + 2 * i) = pk;
    }
  }
}

// ---------------- causal flash attention (R19-proven: 107.4 us) ----------------
__global__ __launch_bounds__(256, 2) void k_attn10(const ushort* __restrict__ qb,
                                                   const ushort* __restrict__ kb,
                                                   const ushort* __restrict__ vT,
                                                   ushort* __restrict__ aout) {
  const int id = blockIdx.x;
  const int qt = (id < 256) ? (15 - (id >> 5)) : ((id - 256) >> 5);
  const int bh = id & 31;
  const int h = bh & 15, b = bh >> 4;

  const int t = threadIdx.x, lane = t & 63, w = t >> 6;
  const int lq = lane & 31, hi = lane >> 5;
  const int kx = (lq >> 3) & 3;

  __shared__ ushort Ks[64 * 200];   // 25600 B
  __shared__ ushort Vs[128 * 72];   // 18432 B

  const ushort* kh = kb + (size_t)(b * 16 + h) * (2048 * 192);
  const ushort* vh = vT + (size_t)(b * 16 + h) * (128 * 2048);

  auto stage = [&](int k0) {
#pragma unroll
    for (int it = 0; it < 7; ++it) {
      int ii = it * 4 + w;
      if (ii < 25) {
        unsigned s = ii * 64 + lane;         // 0..1599
        int r = s / 25, e = s - r * 25;      // r<64, e<25 (e==24 pad)
        int cg = e ^ ((r >> 3) & 3);
        if (cg > 23) cg = 0;
        gload16(kh + (size_t)(k0 + r) * 192 + cg * 8, (char*)Ks + ii * 1024);
      }
    }
#pragma unroll
    for (int it = 0; it < 5; ++it) {
      int ii = it * 4 + w;
      if (ii < 18) {
        unsigned s = ii * 64 + lane;         // 0..1151
        int r = s / 9, e = s - r * 9;        // r<128, e<9 (e==8 pad)
        int cg = e ^ ((r >> 3) & 7);
        if (cg > 7) cg = 0;
        gload16(vh + (size_t)r * 2048 + k0 + cg * 8, (char*)Vs + ii * 1024);
      }
    }
  };

  const int q0 = qt * 128;
  const int q0w = q0 + 32 * w;
  const int qg = q0w + lq;
  const int nkt = qt * 2 + 2;

  bf16x8 qf[12];
  {
    const ushort* qp = qb + ((size_t)(b * 2048 + qg) * 16 + h) * 192 + 8 * hi;
#pragma unroll
    for (int s = 0; s < 12; ++s) qf[s] = *(const bf16x8*)(qp + 16 * s);
  }

  f32x16 oacc[4];
#pragma unroll
  for (int db = 0; db < 4; ++db)
#pragma unroll
    for (int r = 0; r < 16; ++r) oacc[db][r] = 0.f;
  float m = -1e30f, l = 0.f;

  for (int kt = 0; kt < nkt; ++kt) {
    const int k0 = kt * 64;
    stage(k0);
    asm volatile("s_waitcnt vmcnt(0)" ::: "memory");
    __syncthreads();
    if (k0 <= q0w + 31) {
      f32x16 sA, sB;
#pragma unroll
      for (int r = 0; r < 16; ++r) { sA[r] = 0.f; sB[r] = 0.f; }
      __builtin_amdgcn_s_setprio(1);
#pragma unroll
      for (int s = 0; s < 12; ++s) {
        int ch = ((2 * s + hi) ^ kx) << 3;
        bf16x8 kfA = *(const bf16x8*)(Ks + lq * 200 + ch);
        bf16x8 kfB = *(const bf16x8*)(Ks + (lq + 32) * 200 + ch);
        sA = __builtin_amdgcn_mfma_f32_32x32x16_bf16(kfA, qf[s], sA, 0, 0, 0);
        sB = __builtin_amdgcn_mfma_f32_32x32x16_bf16(kfB, qf[s], sB, 0, 0, 0);
      }
      __builtin_amdgcn_s_setprio(0);
      float svA[16], svB[16];
#pragma unroll
      for (int r = 0; r < 16; ++r) { svA[r] = sA[r]; svB[r] = sB[r]; }
      if (k0 + 63 > q0w) {
#pragma unroll
        for (int r = 0; r < 16; ++r) {
          int kk = (r & 3) + 8 * (r >> 2) + 4 * hi;
          if (k0 + kk > qg) svA[r] = -1e30f;
          if (k0 + 32 + kk > qg) svB[r] = -1e30f;
        }
      }
      float pmax = fmaxf(svA[0], svB[0]);
#pragma unroll
      for (int r = 1; r < 16; ++r) pmax = fmaxf(pmax, fmaxf(svA[r], svB[r]));
      pmax = fmaxf(pmax, __shfl_xor(pmax, 32));
      float smax = pmax * SCALE2;
      if (!__all(smax - m <= 8.0f)) {
        float mnew = fmaxf(m, smax);
        float a = exp2f(m - mnew);
        l *= a;
#pragma unroll
        for (int db = 0; db < 4; ++db)
#pragma unroll
          for (int r = 0; r < 16; ++r) oacc[db][r] *= a;
        m = mnew;
      }
      float eA[16], eB[16]; float sum = 0.f;
#pragma unroll
      for (int r = 0; r < 16; ++r) {
        eA[r] = exp2f(svA[r] * SCALE2 - m);
        eB[r] = exp2f(svB[r] * SCALE2 - m);
        sum += eA[r] + eB[r];
      }
      sum += __shfl_xor(sum, 32);
      l += sum;
      uint32_t pkA[8], pkB[8];
#pragma unroll
      for (int i = 0; i < 8; ++i) {
        pkA[i] = (uint32_t)f2bf(eA[2 * i]) | ((uint32_t)f2bf(eA[2 * i + 1]) << 16);
        pkB[i] = (uint32_t)f2bf(eB[2 * i]) | ((uint32_t)f2bf(eB[2 * i + 1]) << 16);
      }
      uint32_t swA[8], swB[8];
#pragma unroll
      for (int i = 0; i < 8; ++i) {
        swA[i] = (uint32_t)__shfl_xor((int)pkA[i], 32);
        swB[i] = (uint32_t)__shfl_xor((int)pkB[i], 32);
      }
      union { uint32_t u[4]; bf16x8 v; } pA0, pA1, pB0, pB1;
      pA0.u[0] = hi ? swA[2] : pkA[0];
      pA0.u[1] = hi ? swA[3] : pkA[1];
      pA0.u[2] = hi ? pkA[2] : swA[0];
      pA0.u[3] = hi ? pkA[3] : swA[1];
      pA1.u[0] = hi ? swA[6] : pkA[4];
      pA1.u[1] = hi ? swA[7] : pkA[5];
      pA1.u[2] = hi ? pkA[6] : swA[4];
      pA1.u[3] = hi ? pkA[7] : swA[5];
      pB0.u[0] = hi ? swB[2] : pkB[0];
      pB0.u[1] = hi ? swB[3] : pkB[1];
      pB0.u[2] = hi ? pkB[2] : swB[0];
      pB0.u[3] = hi ? pkB[3] : swB[1];
      pB1.u[0] = hi ? swB[6] : pkB[4];
      pB1.u[1] = hi ? swB[7] : pkB[5];
      pB1.u[2] = hi ? pkB[6] : swB[4];
      pB1.u[3] = hi ? pkB[7] : swB[5];
      __builtin_amdgcn_s_setprio(1);
#pragma unroll
      for (int db = 0; db < 4; ++db) {
        const int d = 32 * db + lq;
        const int vx = (d >> 3) & 7;
        const ushort* vr = Vs + d * 72;
        bf16x8 vf0 = *(const bf16x8*)(vr + (((0 + hi) ^ vx) << 3));
        bf16x8 vf1 = *(const bf16x8*)(vr + (((2 + hi) ^ vx) << 3));
        bf16x8 vf2 = *(const bf16x8*)(vr + (((4 + hi) ^ vx) << 3));
        bf16x8 vf3 = *(const bf16x8*)(vr + (((6 + hi) ^ vx) << 3));
        oacc[db] = __builtin_amdgcn_mfma_f32_32x32x16_bf16(vf0, pA0.v, oacc[db], 0, 0, 0);
        oacc[db] = __builtin_amdgcn_mfma_f32_32x32x16_bf16(vf1, pA1.v, oacc[db], 0, 0, 0);
        oacc[db] = __builtin_amdgcn_mfma_f32_32x32x16_bf16(vf2, pB0.v, oacc[db], 0, 0, 0);
        oacc[db] = __builtin_amdgcn_mfma_f32_32x32x16_bf16(vf3, pB1.v, oacc[db], 0, 0, 0);
      }
      __builtin_amdgcn_s_setprio(0);
    }
    asm volatile("s_waitcnt lgkmcnt(0)" ::: "memory");
    __syncthreads();
  }

  float inv = 1.f / l;
  ushort* op = aout + ((size_t)(b * 2048 + qg)) * 2048 + h * 128 + 4 * hi;
#pragma unroll
  for (int db = 0; db < 4; ++db)
#pragma unroll
    for (int i = 0; i < 8; ++i) {
      uint32_t u = (uint32_t)f2bf(oacc[db][2 * i] * inv) |
                   ((uint32_t)f2bf(oacc[db][2 * i + 1] * inv) << 16);
      int dbase = 32 * db + (i & 1) * 2 + (i >> 1) * 8;
      *(uint32_t*)(op + dbase) = u;
    }
}

// ---------------- launcher ----------------
extern "C" void kernel_launch(void* const* d_in, const int* in_sizes, int n_in,
                              void* d_out, int out_size, void* d_ws, size_t ws_size,
                              hipStream_t stream) {
  const float* x = (const float*)d_in[0];
  const float* fcos = (const float*)d_in[1];
  const float* fsin = (const float*)d_in[2];
  const float* wq_a = (const float*)d_in[3];
  const float* qnw = (const float*)d_in[4];
  const float* wq_b = (const float*)d_in[5];
  const float* wkv_a = (const float*)d_in[6];
  const float* kvnw = (const float*)d_in[7];
  const float* wkv_b = (const float*)d_in[8];
  const float* wo = (const float*)d_in[9];
  float* out = (float*)d_out;

  char* ws = (char*)d_ws;
  size_t off = 0;
  auto alloc = [&](size_t bytes) -> char* {
    char* p = ws + off;
    off += (bytes + 255) & ~(size_t)255;
    return p;
  };
  ushort* xb     = (ushort*)alloc(4096ull * 2048 * 2);
  ushort* wqkv_t = (ushort*)alloc(2176ull * 2048 * 2);   // rows 0-1535 wq_a^T, 1536-2111 wkv_a^T, rest pad
  ushort* wqb_t  = (ushort*)alloc(3072ull * 1536 * 2);
  ushort* wkvb_t = (ushort*)alloc(4096ull * 512 * 2);
  ushort* wo_t   = (ushort*)alloc(2048ull * 2048 * 2);
  ushort* cqkv   = (ushort*)alloc(4096ull * 2112 * 2);   // fused q_lora | kv_lora | k_pe (bf16)
  ushort* cqn    = (ushort*)alloc(4096ull * 1536 * 2);
  ushort* ckvn   = (ushort*)alloc(4096ull * 512 * 2);
  ushort* kbuf   = (ushort*)alloc(2ull * 16 * 2048 * 192 * 2);
  ushort* qbuf   = (ushort*)alloc(4096ull * 3072 * 2);   // q projection output
  ushort* aout   = xb;              // reuse: xb dead after fused GEMM1
  ushort* vT     = cqkv;            // vT (16.8MB) aliases cqkv (17.3MB), dead after
                                    // k_norms (R23-proven alias plan).

  // merged: x convert + 5 weight transposes (17024 blocks)
  k_pre<<<17024, dim3(32, 8), 0, stream>>>(
      wq_a, wkv_a, wq_b, wkv_b, wo,
      wqkv_t, wqkv_t + 1536ull * 2048, wqb_t, wkvb_t, wo_t,
      x, xb);

  // fused GEMM1: cqkv = xb @ [wq_a | wkv_a]  (M=4096, K=2048, Nreal=2112), bf16 out
  k_gemm<ushort><<<dim3(17, 32), 256, 0, stream>>>(xb, wqkv_t, cqkv, 2048, 2112);

  // merged norms (8192 blocks) -- last reader of cqkv
  k_norms<<<8192, 256, 0, stream>>>(cqkv, qnw, kvnw, fcos, fsin, cqn, ckvn, kbuf);

  // merged GEMM2(qrope, K=1536, 192 blocks) + GEMM-kv (K=512, 256 blocks),
  // 256^2 dbuf counted-vmcnt engine (R24-proven), 448 blocks x 512 thr
  k_gemm_qkv256<<<448, 512, 0, stream>>>(cqn, wqb_t, qbuf, fcos, fsin,
                                         ckvn, wkvb_t, kbuf, vT);

  k_attn10<<<dim3(512), 256, 0, stream>>>(qbuf, kbuf, vT, aout);

  // out = aout @ wo (K=2048, N=2048), fp32 out
  k_gemm<float><<<dim3(16, 32), 256, 0, stream>>>(aout, wo_t, out, 2048, 2048);
}

// Round 26
// 326.490 us; speedup vs baseline: 1.0707x; 1.0707x over previous
//
#include <hip/hip_runtime.h>
#include <cstdint>
#include <cstddef>

// ---------------- common types / helpers ----------------
typedef __attribute__((ext_vector_type(8))) short bf16x8;
typedef __attribute__((ext_vector_type(4))) float f32x4;
typedef __attribute__((ext_vector_type(16))) float f32x16;

#define S_LEN 2048
#define SCALE2 0.10411754f   // 192^-0.5 * log2(e)

__device__ __forceinline__ ushort f2bf(float f) {
  uint32_t u = __float_as_uint(f);
  u = (u + 0x7FFFu + ((u >> 16) & 1u)) >> 16;
  return (ushort)u;
}
__device__ __forceinline__ float bf2f(ushort u) {
  return __uint_as_float(((uint32_t)u) << 16);
}

typedef __attribute__((address_space(1))) void GV;
typedef __attribute__((address_space(3))) void LV;
__device__ __forceinline__ void gload16(const void* g, void* l) {
  __builtin_amdgcn_global_load_lds((GV*)g, (LV*)l, 16, 0, 0);
}

__device__ __forceinline__ void store_out(float* p, float v) { *p = v; }
__device__ __forceinline__ void store_out(ushort* p, float v) { *p = f2bf(v); }

// ---------------- merged preprocessing: 5 weight transposes + x convert ----------------
__global__ void k_pre(const float* __restrict__ s0, const float* __restrict__ s1,
                      const float* __restrict__ s2, const float* __restrict__ s3,
                      const float* __restrict__ s4,
                      ushort* __restrict__ d0, ushort* __restrict__ d1,
                      ushort* __restrict__ d2, ushort* __restrict__ d3,
                      ushort* __restrict__ d4,
                      const float* __restrict__ x, ushort* __restrict__ xb) {
  int id = blockIdx.x;
  if (id >= 14976) {            // convert segment: 2048 blocks, grid-stride
    int ft = threadIdx.y * 32 + threadIdx.x;
    int i = (id - 14976) * 256 + ft;
    const int n4 = 4096 * 2048 / 4, stride = 2048 * 256;
    for (; i < n4; i += stride) {
      float4 v = reinterpret_cast<const float4*>(x)[i];
      ushort4 o;
      o.x = f2bf(v.x); o.y = f2bf(v.y); o.z = f2bf(v.z); o.w = f2bf(v.w);
      reinterpret_cast<ushort4*>(xb)[i] = o;
    }
    return;
  }
  __shared__ float tile[32][33];
  const float* in; ushort* out; int R, C, gx, lid;
  if (id < 3072)        { in = s0; out = d0; R = 2048; C = 1536; gx = 48;  lid = id; }
  else if (id < 4224)   { in = s1; out = d1; R = 2048; C = 576;  gx = 18;  lid = id - 3072; }
  else if (id < 8832)   { in = s2; out = d2; R = 1536; C = 3072; gx = 96;  lid = id - 4224; }
  else if (id < 10880)  { in = s3; out = d3; R = 512;  C = 4096; gx = 128; lid = id - 8832; }
  else                  { in = s4; out = d4; R = 2048; C = 2048; gx = 64;  lid = id - 10880; }
  int c0 = (lid % gx) * 32, r0 = (lid / gx) * 32;
  int tx = threadIdx.x, ty = threadIdx.y;
#pragma unroll
  for (int i = 0; i < 32; i += 8) {
    int r = r0 + ty + i, c = c0 + tx;
    if (r < R && c < C) tile[ty + i][tx] = in[(size_t)r * C + c];
  }
  __syncthreads();
#pragma unroll
  for (int i = 0; i < 32; i += 8) {
    int c = c0 + ty + i, r = r0 + tx;
    if (r < R && c < C) out[(size_t)c * R + r] = f2bf(tile[tx][ty + i]);
  }
}

// ---------------- 128x128 BK=64 bf16 GEMM (R15-proven single-buffer form) ----------------
// R25's dbuf counted-vmcnt variant REGRESSED here (-17us): at 128^2 the
// single-buffer form runs 4 blocks/CU; halving to 2 (72KB dbuf) loses more
// TLP than even a correct counted pipeline regains (R16 repeated with the
// protocol fixed -> cause is occupancy, not schedule). Counted dbuf pays
// only at 1 block/CU residency (256^2 engine below).
template <typename OUT>
__global__ __launch_bounds__(256) void k_gemm(const ushort* __restrict__ A,
                                              const ushort* __restrict__ Bt,
                                              OUT* __restrict__ C, int K, int Nreal) {
  __shared__ ushort As[128 * 72];   // 18432 B
  __shared__ ushort Bs[128 * 72];   // 18432 B
  const int t = threadIdx.x, lane = t & 63, w = t >> 6;
  const int nwg = gridDim.x * gridDim.y;
  const int wg = blockIdx.y * gridDim.x + blockIdx.x;
  const int swz = (wg & 7) * (nwg >> 3) + (wg >> 3);
  const int m0 = (swz / gridDim.x) * 128, n0 = (swz % gridDim.x) * 128;
  const int wm = (w >> 1) * 64, wn = (w & 1) * 64;
  const int g = lane >> 4, q = lane & 15;
  f32x4 acc[4][4] = {};
  for (int kt = 0; kt < K; kt += 64) {
#pragma unroll
    for (int it = 0; it < 5; ++it) {
      int ii = it * 4 + w;
      if (ii < 18) {
        unsigned s = ii * 64 + lane;         // 0..1151
        int r = s / 9, e = s - r * 9;        // r<128, e<9
        int cg = e ^ ((r >> 3) & 7);
        if (cg > 7) cg = 0;                  // pad slot -> dummy load
        gload16(A + (size_t)(m0 + r) * K + kt + cg * 8, (char*)As + ii * 1024);
        gload16(Bt + (size_t)(n0 + r) * K + kt + cg * 8, (char*)Bs + ii * 1024);
      }
    }
    asm volatile("s_waitcnt vmcnt(0)" ::: "memory");
    __syncthreads();
#pragma unroll
    for (int kh = 0; kh < 2; ++kh) {
      bf16x8 af[4], bfr[4];
#pragma unroll
      for (int mi = 0; mi < 4; mi++) {
        int row = wm + 16 * mi + q;
        int rx = (row >> 3) & 7;
        af[mi] = *(const bf16x8*)(As + row * 72 + (((kh * 4 + g) ^ rx) << 3));
      }
#pragma unroll
      for (int ni = 0; ni < 4; ni++) {
        int row = wn + 16 * ni + q;
        int rx = (row >> 3) & 7;
        bfr[ni] = *(const bf16x8*)(Bs + row * 72 + (((kh * 4 + g) ^ rx) << 3));
      }
#pragma unroll
      for (int mi = 0; mi < 4; mi++)
#pragma unroll
        for (int ni = 0; ni < 4; ni++)
          acc[mi][ni] = __builtin_amdgcn_mfma_f32_16x16x32_bf16(af[mi], bfr[ni], acc[mi][ni], 0, 0, 0);
    }
    __syncthreads();
  }
#pragma unroll
  for (int mi = 0; mi < 4; mi++)
#pragma unroll
    for (int ni = 0; ni < 4; ni++) {
      int col = n0 + wn + 16 * ni + q;
      if (col < Nreal) {
        int row = m0 + wm + 16 * mi + 4 * g;
#pragma unroll
        for (int r = 0; r < 4; r++)
          store_out(&C[(size_t)(row + r) * Nreal + col], acc[mi][ni][r]);
      }
    }
}

// ---------------- merged GEMM2(qrope)+GEMM-kv: 256x256 BK=64 dbuf counted-vmcnt (R24-proven) ----------------
__global__ __launch_bounds__(512, 1) void k_gemm_qkv256(
    const ushort* __restrict__ A1, const ushort* __restrict__ Bt1,
    ushort* __restrict__ C1,
    const float* __restrict__ cosT, const float* __restrict__ sinT,
    const ushort* __restrict__ A2, const ushort* __restrict__ Bt2,
    ushort* __restrict__ kbuf, ushort* __restrict__ vT) {
  __shared__ __align__(16) char lds[2][4][18432];
  const int t = threadIdx.x, lane = t & 63, w = t >> 6;
  const int q = lane & 15, g = lane >> 4;
  const int wm = w >> 2, wn = w & 3;
  const int id = blockIdx.x;
  const bool seg1 = (id < 192);
  const ushort* A  = seg1 ? A1 : A2;
  const ushort* Bt = seg1 ? Bt1 : Bt2;
  const int K   = seg1 ? 1536 : 512;
  const int gx  = seg1 ? 12 : 16;
  const int nwg = seg1 ? 192 : 256;
  const int wg  = seg1 ? id : id - 192;
  const int swz = (wg & 7) * (nwg >> 3) + (wg >> 3);
  const int m0 = (swz / gx) * 256, n0 = (swz % gx) * 256;
  const int nt = K >> 6;

  auto stageTile = [&](int kt, int p) {
#pragma unroll
    for (int it = 0; it < 9; ++it) {
      int u = it * 512 + (w << 6);
      int hh = u / 1152;
      int s0 = u - hh * 1152;
      int s = s0 + lane;
      int r = s / 9, c = s - r * 9;
      if (c > 7) c = 0;
      const ushort* src = (hh < 2) ? (A + (size_t)(m0 + (hh << 7) + r) * K)
                                   : (Bt + (size_t)(n0 + ((hh - 2) << 7) + r) * K);
      gload16(src + kt * 64 + c * 8, &lds[p][hh][s0 * 16]);
    }
  };

  f32x4 acc[8][4] = {};
  stageTile(0, 0);
  asm volatile("" ::: "memory");
  stageTile(1, 1);

  for (int kt = 0; kt < nt; ++kt) {
    const int p = kt & 1;
    if (kt == 0 || kt + 1 >= nt) asm volatile("s_waitcnt vmcnt(0)" ::: "memory");
    else                         asm volatile("s_waitcnt vmcnt(9)" ::: "memory");
    __builtin_amdgcn_s_barrier();
    asm volatile("" ::: "memory");
    const char* LA = &lds[p][wm][0];
    const char* LB = &lds[p][2 + (wn >> 1)][0];
    const int brow0 = (wn & 1) * 64;
    bf16x8 bfr[4][2];
#pragma unroll
    for (int ni = 0; ni < 4; ++ni) {
      bfr[ni][0] = *(const bf16x8*)(LB + (brow0 + ni * 16 + q) * 144 + 16 * g);
      bfr[ni][1] = *(const bf16x8*)(LB + (brow0 + ni * 16 + q) * 144 + 64 + 16 * g);
    }
    __builtin_amdgcn_s_setprio(1);
#pragma unroll
    for (int mi = 0; mi < 8; ++mi) {
      bf16x8 a0 = *(const bf16x8*)(LA + (mi * 16 + q) * 144 + 16 * g);
      bf16x8 a1 = *(const bf16x8*)(LA + (mi * 16 + q) * 144 + 64 + 16 * g);
#pragma unroll
      for (int ni = 0; ni < 4; ++ni)
        acc[mi][ni] = __builtin_amdgcn_mfma_f32_16x16x32_bf16(a0, bfr[ni][0], acc[mi][ni], 0, 0, 0);
#pragma unroll
      for (int ni = 0; ni < 4; ++ni)
        acc[mi][ni] = __builtin_amdgcn_mfma_f32_16x16x32_bf16(a1, bfr[ni][1], acc[mi][ni], 0, 0, 0);
    }
    __builtin_amdgcn_s_setprio(0);
    asm volatile("s_waitcnt lgkmcnt(0)" ::: "memory");
    __builtin_amdgcn_s_barrier();
    asm volatile("" ::: "memory");
    if (kt + 2 < nt) stageTile(kt + 2, p);
  }

  if (seg1) {
#pragma unroll
    for (int mi = 0; mi < 8; ++mi)
#pragma unroll
      for (int ni = 0; ni < 4; ++ni) {
        int col = n0 + wn * 64 + ni * 16 + q;
        int hoff = col % 192;
        int row = m0 + wm * 128 + mi * 16 + 4 * g;
        if (hoff < 128) {
#pragma unroll
          for (int r = 0; r < 4; r++)
            C1[(size_t)(row + r) * 3072 + col] = f2bf(acc[mi][ni][r]);
        } else {
          int i = (hoff - 128) >> 1;
#pragma unroll
          for (int r = 0; r < 4; r++) {
            int s2 = (row + r) & 2047;
            float c = cosT[s2 * 32 + i], sn = sinT[s2 * 32 + i];
            float v = acc[mi][ni][r];
            float pv = __shfl_xor(v, 1);
            float res = (q & 1) ? (pv * sn + v * c) : (v * c - pv * sn);
            C1[(size_t)(row + r) * 3072 + col] = f2bf(res);
          }
        }
      }
  } else {
#pragma unroll
    for (int mi = 0; mi < 8; ++mi)
#pragma unroll
      for (int ni = 0; ni < 4; ++ni) {
        int col = n0 + wn * 64 + ni * 16 + q;
        int hh = col >> 8, jj = col & 255;
        int row0 = m0 + wm * 128 + mi * 16 + 4 * g;
#pragma unroll
        for (int r = 0; r < 4; r++) {
          int tok = row0 + r;
          int bb = tok >> 11, ss = tok & 2047;
          ushort v = f2bf(acc[mi][ni][r]);
          if (jj < 128)
            kbuf[((size_t)(bb * 16 + hh) * 2048 + ss) * 192 + jj] = v;
          else
            vT[((size_t)(bb * 16 + hh) * 128 + (jj - 128)) * 2048 + ss] = v;
        }
      }
  }
}

// ---------------- merged norms: rmsnorm(q) + kvnorm+rope (8192 blocks) ----------------
__global__ void k_norms(const ushort* __restrict__ cqkv, const float* __restrict__ qnw,
                        const float* __restrict__ kvnw,
                        const float* __restrict__ cosT, const float* __restrict__ sinT,
                        ushort* __restrict__ cqn, ushort* __restrict__ ckvn,
                        ushort* __restrict__ kbuf) {
  __shared__ float red[4];
  int id = blockIdx.x;
  if (id < 4096) {
    int row = id;
    const ushort* x = cqkv + (size_t)row * 2112;
    ushort* o = cqn + (size_t)row * 1536;
    float ss = 0.f;
    for (int i = threadIdx.x; i < 1536; i += 256) { float v = bf2f(x[i]); ss += v * v; }
#pragma unroll
    for (int m = 1; m < 64; m <<= 1) ss += __shfl_xor(ss, m);
    if ((threadIdx.x & 63) == 0) red[threadIdx.x >> 6] = ss;
    __syncthreads();
    float tot = red[0] + red[1] + red[2] + red[3];
    float sc = rsqrtf(tot / 1536.f + 1e-6f);
    for (int i = threadIdx.x; i < 1536; i += 256) o[i] = f2bf(bf2f(x[i]) * sc * qnw[i]);
  } else {
    int tok = id - 4096, b = tok >> 11, s = tok & 2047;
    const ushort* x = cqkv + (size_t)tok * 2112 + 1536;
    float ss = 0.f;
    for (int i = threadIdx.x; i < 512; i += 256) { float v = bf2f(x[i]); ss += v * v; }
#pragma unroll
    for (int m = 1; m < 64; m <<= 1) ss += __shfl_xor(ss, m);
    if ((threadIdx.x & 63) == 0) red[threadIdx.x >> 6] = ss;
    __syncthreads();
    float tot = red[0] + red[1] + red[2] + red[3];
    float sc = rsqrtf(tot / 512.f + 1e-6f);
    for (int i = threadIdx.x; i < 512; i += 256) ckvn[(size_t)tok * 512 + i] = f2bf(bf2f(x[i]) * sc * kvnw[i]);
    if (threadIdx.x < 32) {
      int i = threadIdx.x;
      float xr = bf2f(x[512 + 2 * i]), xi = bf2f(x[512 + 2 * i + 1]);
      float c = cosT[s * 32 + i], sn = sinT[s * 32 + i];
      uint32_t lo = f2bf(xr * c - xi * sn);
      uint32_t hi = f2bf(xr * sn + xi * c);
      uint32_t pk = lo | (hi << 16);
#pragma unroll
      for (int h = 0; h < 16; ++h)
        *(uint32_t*)(kbuf + ((size_t)(b * 16 + h) * 2048 + s) * 192 + 128 + 2 * i) = pk;
    }
  }
}

// ---------------- causal flash attention (R19-proven: 107.4 us) ----------------
__global__ __launch_bounds__(256, 2) void k_attn10(const ushort* __restrict__ qb,
                                                   const ushort* __restrict__ kb,
                                                   const ushort* __restrict__ vT,
                                                   ushort* __restrict__ aout) {
  const int id = blockIdx.x;
  const int qt = (id < 256) ? (15 - (id >> 5)) : ((id - 256) >> 5);
  const int bh = id & 31;
  const int h = bh & 15, b = bh >> 4;

  const int t = threadIdx.x, lane = t & 63, w = t >> 6;
  const int lq = lane & 31, hi = lane >> 5;
  const int kx = (lq >> 3) & 3;

  __shared__ ushort Ks[64 * 200];   // 25600 B
  __shared__ ushort Vs[128 * 72];   // 18432 B

  const ushort* kh = kb + (size_t)(b * 16 + h) * (2048 * 192);
  const ushort* vh = vT + (size_t)(b * 16 + h) * (128 * 2048);

  auto stage = [&](int k0) {
#pragma unroll
    for (int it = 0; it < 7; ++it) {
      int ii = it * 4 + w;
      if (ii < 25) {
        unsigned s = ii * 64 + lane;         // 0..1599
        int r = s / 25, e = s - r * 25;      // r<64, e<25 (e==24 pad)
        int cg = e ^ ((r >> 3) & 3);
        if (cg > 23) cg = 0;
        gload16(kh + (size_t)(k0 + r) * 192 + cg * 8, (char*)Ks + ii * 1024);
      }
    }
#pragma unroll
    for (int it = 0; it < 5; ++it) {
      int ii = it * 4 + w;
      if (ii < 18) {
        unsigned s = ii * 64 + lane;         // 0..1151
        int r = s / 9, e = s - r * 9;        // r<128, e<9 (e==8 pad)
        int cg = e ^ ((r >> 3) & 7);
        if (cg > 7) cg = 0;
        gload16(vh + (size_t)r * 2048 + k0 + cg * 8, (char*)Vs + ii * 1024);
      }
    }
  };

  const int q0 = qt * 128;
  const int q0w = q0 + 32 * w;
  const int qg = q0w + lq;
  const int nkt = qt * 2 + 2;

  bf16x8 qf[12];
  {
    const ushort* qp = qb + ((size_t)(b * 2048 + qg) * 16 + h) * 192 + 8 * hi;
#pragma unroll
    for (int s = 0; s < 12; ++s) qf[s] = *(const bf16x8*)(qp + 16 * s);
  }

  f32x16 oacc[4];
#pragma unroll
  for (int db = 0; db < 4; ++db)
#pragma unroll
    for (int r = 0; r < 16; ++r) oacc[db][r] = 0.f;
  float m = -1e30f, l = 0.f;

  for (int kt = 0; kt < nkt; ++kt) {
    const int k0 = kt * 64;
    stage(k0);
    asm volatile("s_waitcnt vmcnt(0)" ::: "memory");
    __syncthreads();
    if (k0 <= q0w + 31) {
      f32x16 sA, sB;
#pragma unroll
      for (int r = 0; r < 16; ++r) { sA[r] = 0.f; sB[r] = 0.f; }
      __builtin_amdgcn_s_setprio(1);
#pragma unroll
      for (int s = 0; s < 12; ++s) {
        int ch = ((2 * s + hi) ^ kx) << 3;
        bf16x8 kfA = *(const bf16x8*)(Ks + lq * 200 + ch);
        bf16x8 kfB = *(const bf16x8*)(Ks + (lq + 32) * 200 + ch);
        sA = __builtin_amdgcn_mfma_f32_32x32x16_bf16(kfA, qf[s], sA, 0, 0, 0);
        sB = __builtin_amdgcn_mfma_f32_32x32x16_bf16(kfB, qf[s], sB, 0, 0, 0);
      }
      __builtin_amdgcn_s_setprio(0);
      float svA[16], svB[16];
#pragma unroll
      for (int r = 0; r < 16; ++r) { svA[r] = sA[r]; svB[r] = sB[r]; }
      if (k0 + 63 > q0w) {
#pragma unroll
        for (int r = 0; r < 16; ++r) {
          int kk = (r & 3) + 8 * (r >> 2) + 4 * hi;
          if (k0 + kk > qg) svA[r] = -1e30f;
          if (k0 + 32 + kk > qg) svB[r] = -1e30f;
        }
      }
      float pmax = fmaxf(svA[0], svB[0]);
#pragma unroll
      for (int r = 1; r < 16; ++r) pmax = fmaxf(pmax, fmaxf(svA[r], svB[r]));
      pmax = fmaxf(pmax, __shfl_xor(pmax, 32));
      float smax = pmax * SCALE2;
      if (!__all(smax - m <= 8.0f)) {
        float mnew = fmaxf(m, smax);
        float a = exp2f(m - mnew);
        l *= a;
#pragma unroll
        for (int db = 0; db < 4; ++db)
#pragma unroll
          for (int r = 0; r < 16; ++r) oacc[db][r] *= a;
        m = mnew;
      }
      float eA[16], eB[16]; float sum = 0.f;
#pragma unroll
      for (int r = 0; r < 16; ++r) {
        eA[r] = exp2f(svA[r] * SCALE2 - m);
        eB[r] = exp2f(svB[r] * SCALE2 - m);
        sum += eA[r] + eB[r];
      }
      sum += __shfl_xor(sum, 32);
      l += sum;
      uint32_t pkA[8], pkB[8];
#pragma unroll
      for (int i = 0; i < 8; ++i) {
        pkA[i] = (uint32_t)f2bf(eA[2 * i]) | ((uint32_t)f2bf(eA[2 * i + 1]) << 16);
        pkB[i] = (uint32_t)f2bf(eB[2 * i]) | ((uint32_t)f2bf(eB[2 * i + 1]) << 16);
      }
      uint32_t swA[8], swB[8];
#pragma unroll
      for (int i = 0; i < 8; ++i) {
        swA[i] = (uint32_t)__shfl_xor((int)pkA[i], 32);
        swB[i] = (uint32_t)__shfl_xor((int)pkB[i], 32);
      }
      union { uint32_t u[4]; bf16x8 v; } pA0, pA1, pB0, pB1;
      pA0.u[0] = hi ? swA[2] : pkA[0];
      pA0.u[1] = hi ? swA[3] : pkA[1];
      pA0.u[2] = hi ? pkA[2] : swA[0];
      pA0.u[3] = hi ? pkA[3] : swA[1];
      pA1.u[0] = hi ? swA[6] : pkA[4];
      pA1.u[1] = hi ? swA[7] : pkA[5];
      pA1.u[2] = hi ? pkA[6] : swA[4];
      pA1.u[3] = hi ? pkA[7] : swA[5];
      pB0.u[0] = hi ? swB[2] : pkB[0];
      pB0.u[1] = hi ? swB[3] : pkB[1];
      pB0.u[2] = hi ? pkB[2] : swB[0];
      pB0.u[3] = hi ? pkB[3] : swB[1];
      pB1.u[0] = hi ? swB[6] : pkB[4];
      pB1.u[1] = hi ? swB[7] : pkB[5];
      pB1.u[2] = hi ? pkB[6] : swB[4];
      pB1.u[3] = hi ? pkB[7] : swB[5];
      __builtin_amdgcn_s_setprio(1);
#pragma unroll
      for (int db = 0; db < 4; ++db) {
        const int d = 32 * db + lq;
        const int vx = (d >> 3) & 7;
        const ushort* vr = Vs + d * 72;
        bf16x8 vf0 = *(const bf16x8*)(vr + (((0 + hi) ^ vx) << 3));
        bf16x8 vf1 = *(const bf16x8*)(vr + (((2 + hi) ^ vx) << 3));
        bf16x8 vf2 = *(const bf16x8*)(vr + (((4 + hi) ^ vx) << 3));
        bf16x8 vf3 = *(const bf16x8*)(vr + (((6 + hi) ^ vx) << 3));
        oacc[db] = __builtin_amdgcn_mfma_f32_32x32x16_bf16(vf0, pA0.v, oacc[db], 0, 0, 0);
        oacc[db] = __builtin_amdgcn_mfma_f32_32x32x16_bf16(vf1, pA1.v, oacc[db], 0, 0, 0);
        oacc[db] = __builtin_amdgcn_mfma_f32_32x32x16_bf16(vf2, pB0.v, oacc[db], 0, 0, 0);
        oacc[db] = __builtin_amdgcn_mfma_f32_32x32x16_bf16(vf3, pB1.v, oacc[db], 0, 0, 0);
      }
      __builtin_amdgcn_s_setprio(0);
    }
    asm volatile("s_waitcnt lgkmcnt(0)" ::: "memory");
    __syncthreads();
  }

  float inv = 1.f / l;
  ushort* op = aout + ((size_t)(b * 2048 + qg)) * 2048 + h * 128 + 4 * hi;
#pragma unroll
  for (int db = 0; db < 4; ++db)
#pragma unroll
    for (int i = 0; i < 8; ++i) {
      uint32_t u = (uint32_t)f2bf(oacc[db][2 * i] * inv) |
                   ((uint32_t)f2bf(oacc[db][2 * i + 1] * inv) << 16);
      int dbase = 32 * db + (i & 1) * 2 + (i >> 1) * 8;
      *(uint32_t*)(op + dbase) = u;
    }
}

// ---------------- launcher ----------------
extern "C" void kernel_launch(void* const* d_in, const int* in_sizes, int n_in,
                              void* d_out, int out_size, void* d_ws, size_t ws_size,
                              hipStream_t stream) {
  const float* x = (const float*)d_in[0];
  const float* fcos = (const float*)d_in[1];
  const float* fsin = (const float*)d_in[2];
  const float* wq_a = (const float*)d_in[3];
  const float* qnw = (const float*)d_in[4];
  const float* wq_b = (const float*)d_in[5];
  const float* wkv_a = (const float*)d_in[6];
  const float* kvnw = (const float*)d_in[7];
  const float* wkv_b = (const float*)d_in[8];
  const float* wo = (const float*)d_in[9];
  float* out = (float*)d_out;

  char* ws = (char*)d_ws;
  size_t off = 0;
  auto alloc = [&](size_t bytes) -> char* {
    char* p = ws + off;
    off += (bytes + 255) & ~(size_t)255;
    return p;
  };
  ushort* xb     = (ushort*)alloc(4096ull * 2048 * 2);
  ushort* wqkv_t = (ushort*)alloc(2176ull * 2048 * 2);   // rows 0-1535 wq_a^T, 1536-2111 wkv_a^T, rest pad
  ushort* wqb_t  = (ushort*)alloc(3072ull * 1536 * 2);
  ushort* wkvb_t = (ushort*)alloc(4096ull * 512 * 2);
  ushort* wo_t   = (ushort*)alloc(2048ull * 2048 * 2);
  ushort* cqkv   = (ushort*)alloc(4096ull * 2112 * 2);   // fused q_lora | kv_lora | k_pe (bf16)
  ushort* cqn    = (ushort*)alloc(4096ull * 1536 * 2);
  ushort* ckvn   = (ushort*)alloc(4096ull * 512 * 2);
  ushort* kbuf   = (ushort*)alloc(2ull * 16 * 2048 * 192 * 2);
  ushort* qbuf   = (ushort*)alloc(4096ull * 3072 * 2);   // q projection output
  ushort* aout   = xb;              // reuse: xb dead after fused GEMM1
  ushort* vT     = cqkv;            // vT (16.8MB) aliases cqkv (17.3MB), dead after
                                    // k_norms (R23-proven alias plan).

  // merged: x convert + 5 weight transposes (17024 blocks)
  k_pre<<<17024, dim3(32, 8), 0, stream>>>(
      wq_a, wkv_a, wq_b, wkv_b, wo,
      wqkv_t, wqkv_t + 1536ull * 2048, wqb_t, wkvb_t, wo_t,
      x, xb);

  // fused GEMM1: cqkv = xb @ [wq_a | wkv_a]  (M=4096, K=2048, Nreal=2112), bf16 out
  k_gemm<ushort><<<dim3(17, 32), 256, 0, stream>>>(xb, wqkv_t, cqkv, 2048, 2112);

  // merged norms (8192 blocks) -- last reader of cqkv
  k_norms<<<8192, 256, 0, stream>>>(cqkv, qnw, kvnw, fcos, fsin, cqn, ckvn, kbuf);

  // merged GEMM2(qrope, K=1536, 192 blocks) + GEMM-kv (K=512, 256 blocks),
  // 256^2 dbuf counted-vmcnt engine (R24-proven), 448 blocks x 512 thr
  k_gemm_qkv256<<<448, 512, 0, stream>>>(cqn, wqb_t, qbuf, fcos, fsin,
                                         ckvn, wkvb_t, kbuf, vT);

  k_attn10<<<dim3(512), 256, 0, stream>>>(qbuf, kbuf, vT, aout);

  // out = aout @ wo (K=2048, N=2048), fp32 out
  k_gemm<float><<<dim3(16, 32), 256, 0, stream>>>(aout, wo_t, out, 2048, 2048);
}